// Round 7
// baseline (91.483 us; speedup 1.0000x reference)
//
#include <hip/hip_runtime.h>
#include <math.h>
#include <limits.h>

#define IN_FEATURES 1024
#define OUT_FEATURES 512
#define N_PULSE 10
#define NCOL 1034
#define BATCH 32
#define MIN_W_ARG -0.3678794411714423

#define NSEG 16
#define SEG 66                          /* 16*66 = 1056 scan steps */
#define SCAN (NSEG * SEG)
#define TBLN 1088                       /* table entries (>= SCAN+1, 16-mult) */

/* packed per-b table: [ord i32 TBLN][ts f32 TBLN][z f64 TBLN][zt f64 TBLN] */
#define OFF_TS  (TBLN * 4)
#define OFF_Z   (TBLN * 8)
#define OFF_ZT  (TBLN * 16)
#define TBL_BYTES (TBLN * 24)           /* 26112, 16-divisible */

#define PREP_T_BLOCKS 136               /* 17 n-tiles x 8 o-tiles */
#define PREP_R_PARTS 5                  /* ceil(1034/256) rank parts per b */
#define PREP_BLOCKS (PREP_T_BLOCKS + BATCH * PREP_R_PARTS)   /* 296 */

// ---------- Kernel 1 (merged prep): transpose | rank-sort+z-precompute -------
__global__ __launch_bounds__(256, 1) void prep_kernel(
        const float* __restrict__ w, float* __restrict__ wT,
        const float* __restrict__ x, const float* __restrict__ pulse,
        char* __restrict__ tbl) {
    __shared__ char smem_u[64 * 65 * 4];       // max(transpose tile, rank arrays)
    const int tid = threadIdx.x;

    if (blockIdx.x < PREP_T_BLOCKS) {
        // ---- tiled transpose [O,N] -> [N,O], coalesced both ways ----
        float (*tile)[65] = (float (*)[65])smem_u;
        const int n0 = (blockIdx.x % 17) * 64;
        const int o0 = (blockIdx.x / 17) * 64;
        const int tx = tid & 63, ty = tid >> 6;
        #pragma unroll
        for (int r = 0; r < 16; ++r) {
            int ol = r * 4 + ty, n = n0 + tx;
            if (n < NCOL) tile[ol][tx] = w[(o0 + ol) * NCOL + n];
        }
        __syncthreads();
        #pragma unroll
        for (int r = 0; r < 16; ++r) {
            int nl = r * 4 + ty, n = n0 + nl;
            if (n < NCOL) wT[n * OUT_FEATURES + o0 + tx] = tile[tx][nl];
        }
    } else {
        // ---- stable argsort by rank-count: key64=(mono(t)<<11)|idx ----
        unsigned long long* sk = (unsigned long long*)smem_u;
        float* keyf = (float*)(smem_u + TBLN * 8);
        const int rb = blockIdx.x - PREP_T_BLOCKS;
        const int b = rb / PREP_R_PARTS, part = rb % PREP_R_PARTS;

        for (int e = tid; e < TBLN; e += 256) {
            if (e < NCOL) {
                float t = (e < IN_FEATURES) ? x[b * IN_FEATURES + e]
                                            : pulse[e - IN_FEATURES];
                unsigned u = __float_as_uint(t);
                u = (u & 0x80000000u) ? ~u : (u | 0x80000000u);
                sk[e] = ((unsigned long long)u << 11) | (unsigned)e;
                keyf[e] = t;
            } else {
                sk[e] = 0xFFFFFFFFFFFFFFFFULL;    // pad: never counted
            }
        }
        __syncthreads();

        char* base = tbl + b * TBL_BYTES;
        int*    ordg = (int*)base;
        float*  tsg  = (float*)(base + OFF_TS);
        double* zg   = (double*)(base + OFF_Z);
        double* ztg  = (double*)(base + OFF_ZT);

        const int e = part * 256 + tid;
        if (e < NCOL) {
            unsigned long long mk = sk[e];
            int r = 0;
            for (int j0 = 0; j0 < TBLN; j0 += 16) {
                unsigned long long c[16];
                #pragma unroll
                for (int i = 0; i < 16; ++i) c[i] = sk[j0 + i];
                #pragma unroll
                for (int i = 0; i < 16; ++i) r += (c[i] < mk);
            }
            float t = keyf[e];
            double zv = exp((double)t);
            ordg[r] = e; tsg[r] = t; zg[r] = zv; ztg[r] = zv * (double)t;
        }
        if (part == PREP_R_PARTS - 1) {
            int p = 1024 + tid;                    // pad entries [1034,1088)
            if (p >= NCOL && p < TBLN) {
                ordg[p] = 0; tsg[p] = -1.0f; zg[p] = 0.0; ztg[p] = 0.0;
            }
        }
    }
}

// ------------------------- Lambert W0 on [-1/e, 0] ---------------------------
__device__ __forceinline__ double lambertw0(double xx) {
    const double e = 2.718281828459045;
    double w = (xx < -0.25) ? (-1.0 + sqrt(fmax(2.0 * (1.0 + e * xx), 0.0)))
                            : xx * (1.0 - xx);
    #pragma unroll 4
    for (int i = 0; i < 12; ++i) {
        double ew = exp(w);
        double f  = w * ew - xx;
        double denom = ew * (w + 1.0) - (w + 2.0) * f / (2.0 * (w + 1.0) + 1e-12);
        w = w - f / (denom + 1e-12);
    }
    return w;
}

// ------------- Kernel 2: segmented two-pass scan, 16 waves/block -------------
// Linearity of the cumsum lets 16 waves each own a 66-step k-segment:
//  pass1: per-segment (dA,dB) via independent FMAs; LDS exchange
//  pass2: rescan own segment with exclusive-prefix offset; record first fire
//         (fire = A>1e-10 && A*t_{k+1}-B >= z_{k+1}; same semantics as before:
//          V rising on window, entry implied by previous exit failing)
//  final: wave 0 picks earliest-firing segment, runs ONE Lambert + exact
//         reference check; serial exact fallback for fp-boundary safety.
__global__ __launch_bounds__(1024) void solve_kernel(
        const float* __restrict__ wT,
        const char* __restrict__ tbl,
        float* __restrict__ out) {
    __shared__ char smem[TBL_BYTES];
    __shared__ double segA[NSEG * 64], segB[NSEG * 64];
    __shared__ int    sfk[NSEG * 64];
    __shared__ double sfA[NSEG * 64], sfB[NSEG * 64];

    const int b = blockIdx.x >> 3;
    const int o0 = (blockIdx.x & 7) << 6;
    const int wave = threadIdx.x >> 6;
    const int lane = threadIdx.x & 63;
    const int o = o0 + lane;

    {   // stage packed table: 1632 uint4, ~1.6 per thread
        const uint4* g = (const uint4*)(tbl + b * TBL_BYTES);
        uint4* l = (uint4*)smem;
        for (int e = threadIdx.x; e < TBL_BYTES / 16; e += 1024) l[e] = g[e];
    }
    __syncthreads();
    const int*    ord_l = (const int*)smem;
    const float*  ts_l  = (const float*)(smem + OFF_TS);
    const double* z_l   = (const double*)(smem + OFF_Z);
    const double* zt_l  = (const double*)(smem + OFF_ZT);

    const int k0 = wave * SEG;

    // ---- pass 1: segment partial sums (independent FMAs, 2 accumulators) ----
    {
        double a0 = 0.0, a1 = 0.0, b0 = 0.0, b1 = 0.0;
        for (int c = 0; c < SEG; c += 11) {
            int idx[11]; float buf[11];
            #pragma unroll
            for (int i = 0; i < 11; ++i) idx[i] = ord_l[k0 + c + i];
            #pragma unroll
            for (int i = 0; i < 11; ++i) buf[i] = wT[idx[i] * OUT_FEATURES + o];
            #pragma unroll
            for (int i = 0; i < 11; ++i) {
                double w = (double)buf[i];
                if (i & 1) { a1 = fma(w, z_l[k0 + c + i], a1);
                             b1 = fma(w, zt_l[k0 + c + i], b1); }
                else       { a0 = fma(w, z_l[k0 + c + i], a0);
                             b0 = fma(w, zt_l[k0 + c + i], b0); }
            }
        }
        segA[wave * 64 + lane] = a0 + a1;
        segB[wave * 64 + lane] = b0 + b1;
    }
    __syncthreads();

    // ---- pass 2: rescan own segment with exclusive prefix offset ----
    {
        double A = 0.0, Bv = 0.0;
        for (int s = 0; s < wave; ++s) {
            A  += segA[s * 64 + lane];
            Bv += segB[s * 64 + lane];
        }
        int fk = INT_MAX; double fA = 0.0, fB = 0.0;
        for (int c = 0; c < SEG; c += 11) {
            int idx[11]; float buf[11];
            #pragma unroll
            for (int i = 0; i < 11; ++i) idx[i] = ord_l[k0 + c + i];
            #pragma unroll
            for (int i = 0; i < 11; ++i) buf[i] = wT[idx[i] * OUT_FEATURES + o];
            #pragma unroll
            for (int i = 0; i < 11; ++i) {
                int k = k0 + c + i;
                double w = (double)buf[i];
                A  = fma(w, z_l[k],  A);
                Bv = fma(w, zt_l[k], Bv);
                bool fire = (fk == INT_MAX) & (A > 1e-10) &
                            (fma(A, (double)ts_l[k + 1], -Bv) >= z_l[k + 1]);
                if (fire) { fk = k; fA = A; fB = Bv; }       // -> cndmask
            }
        }
        sfk[wave * 64 + lane] = fk;
        sfA[wave * 64 + lane] = fA;
        sfB[wave * 64 + lane] = fB;
    }
    __syncthreads();

    // ---- final: wave 0, one lane per o ----
    if (wave == 0) {
        int gk = INT_MAX; double gA = 0.0, gB = 0.0;
        #pragma unroll
        for (int s = 0; s < NSEG; ++s) {           // segments k-ordered: min = first
            int k = sfk[s * 64 + lane];
            if (k < gk) { gk = k; gA = sfA[s * 64 + lane]; gB = sfB[s * 64 + lane]; }
        }
        bool done = (gk < NCOL);                   // pad-range fires treated as none

        double AA, BB, tk, tn;
        bool have;
        if (done) {
            AA = gA; BB = gB;
            tk = (double)ts_l[gk];
            tn = (double)ts_l[gk + 1];             // gk <= NCOL-2 (last window can't fire)
            have = true;
        } else {                                   // last-window k = NCOL-1
            double tA = 0.0, tB = 0.0;
            #pragma unroll
            for (int s = 0; s < NSEG; ++s) { tA += segA[s * 64 + lane]; tB += segB[s * 64 + lane]; }
            AA = tA; BB = tB;
            tk = (double)ts_l[NCOL - 1];
            tn = 1000.0;
            have = (AA > 1e-10);
        }

        float result = 1000.0f;
        bool need_fb = false;
        if (have) {
            double boa = BB / AA;
            double arg = -exp(fmin(boa, 80.0)) / AA;
            if (arg >= MIN_W_ARG) {
                double wl = lambertw0(fmin(fmax(arg, MIN_W_ARG), 0.0));
                double tc = boa - wl;
                if (tc >= tk && tc <= tn) result = (float)tc;
                else need_fb = done;
            } else need_fb = done;
        }

        // exact serial fallback (fp-boundary safety net; never taken)
        if (__ballot(need_fb) != 0ULL) {
            double A2 = gA, B2 = gB;
            for (int k = gk + 1; k < NCOL && k >= 0; ++k) {
                if (!need_fb) break;
                double w = (double)wT[ord_l[k] * OUT_FEATURES + o];
                A2 = fma(w, z_l[k], A2);
                B2 = fma(w, zt_l[k], B2);
                if (!(A2 > 1e-10)) continue;
                double tkk = (double)ts_l[k];
                double tnn = (k == NCOL - 1) ? 1000.0 : (double)ts_l[k + 1];
                double boa = B2 / A2;
                double arg = -exp(fmin(boa, 80.0)) / A2;
                if (arg >= MIN_W_ARG) {
                    double wl = lambertw0(fmin(fmax(arg, MIN_W_ARG), 0.0));
                    double tc = boa - wl;
                    if (tc >= tkk && tc <= tnn) { result = (float)tc; need_fb = false; }
                }
            }
        }
        out[b * OUT_FEATURES + o] = result;
    }
}

// --------------------------------- launcher ----------------------------------
extern "C" void kernel_launch(void* const* d_in, const int* in_sizes, int n_in,
                              void* d_out, int out_size, void* d_ws, size_t ws_size,
                              hipStream_t stream) {
    const float* x      = (const float*)d_in[0];
    const float* weight = (const float*)d_in[1];
    const float* pulse  = (const float*)d_in[2];
    float* out = (float*)d_out;

    char* ws = (char*)d_ws;
    float* wT = (float*)ws;                               // 1034*512*4 B
    char*  tbl = ws + (size_t)NCOL * OUT_FEATURES * 4;    // 32 * 26112 B

    hipLaunchKernelGGL(prep_kernel, dim3(PREP_BLOCKS), dim3(256), 0, stream,
                       weight, wT, x, pulse, tbl);
    hipLaunchKernelGGL(solve_kernel, dim3(BATCH * OUT_FEATURES / 64), dim3(1024), 0, stream,
                       wT, tbl, out);
}

// Round 8
// 85.661 us; speedup vs baseline: 1.0680x; 1.0680x over previous
//
#include <hip/hip_runtime.h>
#include <math.h>
#include <limits.h>

#define IN_FEATURES 1024
#define OUT_FEATURES 512
#define N_PULSE 10
#define NCOL 1034
#define BATCH 32
#define MIN_W_ARG -0.3678794411714423

#define NSEG 16
#define SEG 66                          /* 16*66 = 1056 scan steps */
#define TBLN 1088                       /* table entries (>= 1056+1, 16-mult) */

/* packed per-b table: [ord i32 TBLN][ts f32 TBLN][z f64 TBLN][zt f64 TBLN] */
#define OFF_TS  (TBLN * 4)
#define OFF_Z   (TBLN * 8)
#define OFF_ZT  (TBLN * 16)
#define TBL_BYTES (TBLN * 24)           /* 26112 */

#define PREP_T_BLOCKS 136               /* 17 n-tiles x 8 o-tiles */
#define PREP_BLOCKS (PREP_T_BLOCKS + BATCH)

/* rank-block LDS layout (bytes) */
#define R_KM   0                        /* u32 monotone keys [1034] */
#define R_KF   4136                     /* f32 t             [1034] */
#define R_SIDX 8272                     /* i32 slot->elem    [1034] */
#define R_BASE 12408                    /* i32 bucket base   [1025] */
#define R_RUN  16508                    /* i32 running ptr   [1024] */
#define R_PS   20604                    /* i32 scan temp     [256]  */
#define R_BYTES 21632

// ---------- Kernel 1 (prep): transpose | counting-sort rank + z tables -------
__global__ __launch_bounds__(256, 1) void prep_kernel(
        const float* __restrict__ w, float* __restrict__ wT,
        const float* __restrict__ x, const float* __restrict__ pulse,
        char* __restrict__ tbl) {
    __shared__ __align__(16) char smem_u[R_BYTES];   // >= transpose tile 16640
    const int tid = threadIdx.x;

    if (blockIdx.x < PREP_T_BLOCKS) {
        // ---- tiled transpose [O,N] -> [N,O], coalesced both ways ----
        float (*tile)[65] = (float (*)[65])smem_u;
        const int n0 = (blockIdx.x % 17) * 64;
        const int o0 = (blockIdx.x / 17) * 64;
        const int tx = tid & 63, ty = tid >> 6;
        #pragma unroll
        for (int r = 0; r < 16; ++r) {
            int ol = r * 4 + ty, n = n0 + tx;
            if (n < NCOL) tile[ol][tx] = w[(o0 + ol) * NCOL + n];
        }
        __syncthreads();
        #pragma unroll
        for (int r = 0; r < 16; ++r) {
            int nl = r * 4 + ty, n = n0 + nl;
            if (n < NCOL) wT[n * OUT_FEATURES + o0 + tx] = tile[tx][nl];
        }
    } else {
        // ---- counting-sort stable argsort for batch row b ----
        unsigned*  km   = (unsigned*)(smem_u + R_KM);
        float*     kf   = (float*)(smem_u + R_KF);
        int*       sidx = (int*)(smem_u + R_SIDX);
        int*       base = (int*)(smem_u + R_BASE);
        int*       run  = (int*)(smem_u + R_RUN);
        int*       ps   = (int*)(smem_u + R_PS);
        const int b = blockIdx.x - PREP_T_BLOCKS;

        for (int e = tid; e < NCOL; e += 256) {
            float t = (e < IN_FEATURES) ? x[b * IN_FEATURES + e]
                                        : pulse[e - IN_FEATURES];
            kf[e] = t;
            unsigned u = __float_as_uint(t);
            km[e] = (u & 0x80000000u) ? ~u : (u | 0x80000000u);
        }
        for (int i = tid; i < 1024; i += 256) run[i] = 0;
        __syncthreads();

        // histogram: bucket(t) = min(1023, t*1024) is monotone in t
        for (int e = tid; e < NCOL; e += 256) {
            int bk = min(1023, max(0, (int)(kf[e] * 1024.0f)));
            atomicAdd(&run[bk], 1);
        }
        __syncthreads();

        // exclusive prefix over 1024 counts (4 per thread + block scan)
        int c4[4], v = 0;
        #pragma unroll
        for (int j = 0; j < 4; ++j) { c4[j] = run[4 * tid + j]; v += c4[j]; }
        ps[tid] = v;
        __syncthreads();
        for (int off = 1; off < 256; off <<= 1) {
            int xv = (tid >= off) ? ps[tid - off] : 0;
            __syncthreads();
            ps[tid] += xv;
            __syncthreads();
        }
        int ex = ps[tid] - v;
        #pragma unroll
        for (int j = 0; j < 4; ++j) { base[4 * tid + j] = ex; ex += c4[j]; }
        if (tid == 255) base[1024] = ex;            // == NCOL
        __syncthreads();
        for (int i = tid; i < 1024; i += 256) run[i] = base[i];
        __syncthreads();

        // scatter (arbitrary intra-bucket order)
        for (int e = tid; e < NCOL; e += 256) {
            int bk = min(1023, max(0, (int)(kf[e] * 1024.0f)));
            int slot = atomicAdd(&run[bk], 1);
            sidx[slot] = e;
        }
        __syncthreads();

        // exact stable rank within bucket + global table write
        char* gb = tbl + b * TBL_BYTES;
        int*    ordg = (int*)gb;
        float*  tsg  = (float*)(gb + OFF_TS);
        double* zg   = (double*)(gb + OFF_Z);
        double* ztg  = (double*)(gb + OFF_ZT);

        for (int s = tid; s < NCOL; s += 256) {
            int e = sidx[s];
            float t = kf[e];
            unsigned u = km[e];
            int bk = min(1023, max(0, (int)(t * 1024.0f)));
            int lo = base[bk], hi = base[bk + 1];
            int r = lo;
            for (int j = lo; j < hi; ++j) {         // avg 1 element per bucket
                int ej = sidx[j];
                unsigned uj = km[ej];
                r += (uj < u) || (uj == u && ej < e);
            }
            double zv = exp((double)t);
            ordg[r] = e; tsg[r] = t; zg[r] = zv; ztg[r] = zv * (double)t;
        }
        for (int p = NCOL + tid; p < TBLN; p += 256) {
            ordg[p] = 0; tsg[p] = -1.0f; zg[p] = 0.0; ztg[p] = 0.0;
            // pad ts=-1: scan's fire test provably false on pad steps
        }
    }
}

// ------------------------- Lambert W0 on [-1/e, 0] ---------------------------
__device__ __forceinline__ double lambertw0(double xx) {
    const double e = 2.718281828459045;
    double w = (xx < -0.25) ? (-1.0 + sqrt(fmax(2.0 * (1.0 + e * xx), 0.0)))
                            : xx * (1.0 - xx);
    #pragma unroll 4
    for (int i = 0; i < 12; ++i) {
        double ew = exp(w);
        double f  = w * ew - xx;
        double denom = ew * (w + 1.0) - (w + 2.0) * f / (2.0 * (w + 1.0) + 1e-12);
        w = w - f / (denom + 1e-12);
    }
    return w;
}

// ------------- Kernel 2: segmented two-pass scan, 16 waves/block -------------
// pass1: per-segment (dA,dB) partial sums; LDS exchange (cumsum linearity)
// pass2: rescan own 66-step segment with exclusive prefix; first filter-fire
//        (fire = A>1e-10 && A*t_{k+1}-B >= z_{k+1}; V rising on window,
//         entry condition implied by previous window's exit failing)
// final: wave 0 picks earliest segment fire, ONE Lambert + exact reference
//        check; exact serial fallback for fp-boundary safety (never taken).
__global__ __launch_bounds__(1024) void solve_kernel(
        const float* __restrict__ wT,
        const char* __restrict__ tbl,
        float* __restrict__ out) {
    __shared__ char smem[TBL_BYTES];
    __shared__ double segA[NSEG * 64], segB[NSEG * 64];
    __shared__ int    sfk[NSEG * 64];
    __shared__ double sfA[NSEG * 64], sfB[NSEG * 64];

    const int b = blockIdx.x >> 3;
    const int o0 = (blockIdx.x & 7) << 6;
    const int wave = threadIdx.x >> 6;
    const int lane = threadIdx.x & 63;
    const int o = o0 + lane;

    {
        const uint4* g = (const uint4*)(tbl + b * TBL_BYTES);
        uint4* l = (uint4*)smem;
        for (int e = threadIdx.x; e < TBL_BYTES / 16; e += 1024) l[e] = g[e];
    }
    __syncthreads();
    const int*    ord_l = (const int*)smem;
    const float*  ts_l  = (const float*)(smem + OFF_TS);
    const double* z_l   = (const double*)(smem + OFF_Z);
    const double* zt_l  = (const double*)(smem + OFF_ZT);

    const int k0 = wave * SEG;

    // ---- pass 1: segment partial sums ----
    {
        double a0 = 0.0, a1 = 0.0, b0 = 0.0, b1 = 0.0;
        for (int c = 0; c < SEG; c += 11) {
            int idx[11]; float buf[11];
            #pragma unroll
            for (int i = 0; i < 11; ++i) idx[i] = ord_l[k0 + c + i];
            #pragma unroll
            for (int i = 0; i < 11; ++i) buf[i] = wT[idx[i] * OUT_FEATURES + o];
            #pragma unroll
            for (int i = 0; i < 11; ++i) {
                double w = (double)buf[i];
                if (i & 1) { a1 = fma(w, z_l[k0 + c + i], a1);
                             b1 = fma(w, zt_l[k0 + c + i], b1); }
                else       { a0 = fma(w, z_l[k0 + c + i], a0);
                             b0 = fma(w, zt_l[k0 + c + i], b0); }
            }
        }
        segA[wave * 64 + lane] = a0 + a1;
        segB[wave * 64 + lane] = b0 + b1;
    }
    __syncthreads();

    // ---- pass 2: rescan own segment with exclusive prefix offset ----
    {
        double A = 0.0, Bv = 0.0;
        for (int s = 0; s < wave; ++s) {
            A  += segA[s * 64 + lane];
            Bv += segB[s * 64 + lane];
        }
        int fk = INT_MAX; double fA = 0.0, fB = 0.0;
        for (int c = 0; c < SEG; c += 11) {
            int idx[11]; float buf[11];
            #pragma unroll
            for (int i = 0; i < 11; ++i) idx[i] = ord_l[k0 + c + i];
            #pragma unroll
            for (int i = 0; i < 11; ++i) buf[i] = wT[idx[i] * OUT_FEATURES + o];
            #pragma unroll
            for (int i = 0; i < 11; ++i) {
                int k = k0 + c + i;
                double w = (double)buf[i];
                A  = fma(w, z_l[k],  A);
                Bv = fma(w, zt_l[k], Bv);
                bool fire = (fk == INT_MAX) & (A > 1e-10) &
                            (fma(A, (double)ts_l[k + 1], -Bv) >= z_l[k + 1]);
                if (fire) { fk = k; fA = A; fB = Bv; }
            }
        }
        sfk[wave * 64 + lane] = fk;
        sfA[wave * 64 + lane] = fA;
        sfB[wave * 64 + lane] = fB;
    }
    __syncthreads();

    // ---- final: wave 0, one lane per o ----
    if (wave == 0) {
        int gk = INT_MAX; double gA = 0.0, gB = 0.0;
        #pragma unroll
        for (int s = 0; s < NSEG; ++s) {
            int k = sfk[s * 64 + lane];
            if (k < gk) { gk = k; gA = sfA[s * 64 + lane]; gB = sfB[s * 64 + lane]; }
        }
        bool done = (gk < NCOL);

        double AA, BB, tk, tn;
        bool have;
        if (done) {
            AA = gA; BB = gB;
            tk = (double)ts_l[gk];
            tn = (double)ts_l[gk + 1];
            have = true;
        } else {
            double tA = 0.0, tB = 0.0;
            #pragma unroll
            for (int s = 0; s < NSEG; ++s) { tA += segA[s * 64 + lane]; tB += segB[s * 64 + lane]; }
            AA = tA; BB = tB;
            tk = (double)ts_l[NCOL - 1];
            tn = 1000.0;
            have = (AA > 1e-10);
        }

        float result = 1000.0f;
        bool need_fb = false;
        if (have) {
            double boa = BB / AA;
            double arg = -exp(fmin(boa, 80.0)) / AA;
            if (arg >= MIN_W_ARG) {
                double wl = lambertw0(fmin(fmax(arg, MIN_W_ARG), 0.0));
                double tc = boa - wl;
                if (tc >= tk && tc <= tn) result = (float)tc;
                else need_fb = done;
            } else need_fb = done;
        }

        if (__ballot(need_fb) != 0ULL) {
            double A2 = gA, B2 = gB;
            for (int k = gk + 1; k < NCOL && k >= 0; ++k) {
                if (!need_fb) break;
                double w = (double)wT[ord_l[k] * OUT_FEATURES + o];
                A2 = fma(w, z_l[k], A2);
                B2 = fma(w, zt_l[k], B2);
                if (!(A2 > 1e-10)) continue;
                double tkk = (double)ts_l[k];
                double tnn = (k == NCOL - 1) ? 1000.0 : (double)ts_l[k + 1];
                double boa = B2 / A2;
                double arg = -exp(fmin(boa, 80.0)) / A2;
                if (arg >= MIN_W_ARG) {
                    double wl = lambertw0(fmin(fmax(arg, MIN_W_ARG), 0.0));
                    double tc = boa - wl;
                    if (tc >= tkk && tc <= tnn) { result = (float)tc; need_fb = false; }
                }
            }
        }
        out[b * OUT_FEATURES + o] = result;
    }
}

// --------------------------------- launcher ----------------------------------
extern "C" void kernel_launch(void* const* d_in, const int* in_sizes, int n_in,
                              void* d_out, int out_size, void* d_ws, size_t ws_size,
                              hipStream_t stream) {
    const float* x      = (const float*)d_in[0];
    const float* weight = (const float*)d_in[1];
    const float* pulse  = (const float*)d_in[2];
    float* out = (float*)d_out;

    char* ws = (char*)d_ws;
    float* wT = (float*)ws;                               // 1034*512*4 B
    char*  tbl = ws + (size_t)NCOL * OUT_FEATURES * 4;    // 32 * 26112 B

    hipLaunchKernelGGL(prep_kernel, dim3(PREP_BLOCKS), dim3(256), 0, stream,
                       weight, wT, x, pulse, tbl);
    hipLaunchKernelGGL(solve_kernel, dim3(BATCH * OUT_FEATURES / 64), dim3(1024), 0, stream,
                       wT, tbl, out);
}